// Round 10
// baseline (116.612 us; speedup 1.0000x reference)
//
#include <hip/hip_runtime.h>
#include <stdint.h>

// KANLinear: y = silu(x) @ W_b^T + einsum('big,oig->bo', bases(x), W_s * scaler)
// Act = [silu(x) | bases] (B x 4608) bf16, Wc = [W_b | W_s*scaler] (512 x 4608) bf16,
// both pre-XOR-swizzled per 64-elem K-group; one bf16 MFMA GEMM.
// R9: 8-phase-style schedule (T3+T4+T5) at BM256xBN128: 8 waves (4Mx2N),
// ring-3 LDS (48KB tiles, 2-tile staging lookahead), 2 phases/K-tile (kk),
// phase = {8 ds_read early || 3 gload_lds -> barrier -> 16 MFMA -> barrier},
// vmcnt(6) once per tile BEFORE the end barrier (cross-wave visibility).

#define IN_F   512
#define OUT_F  512
#define KDIM   4608
#define BATCH  16384

#define BM 256
#define BN 128
#define BK 64
#define NT (KDIM / BK)                 // 72
#define A_EL (BM * BK)                 // 16384 elems
#define B_EL (BN * BK)                 // 8192 elems
#define T_EL (A_EL + B_EL)             // 24576 elems = 48 KiB
#define LDS_BYTES (3 * T_EL * 2)       // 147456 B

typedef unsigned short u16;
typedef short s16x8 __attribute__((ext_vector_type(8)));
typedef float f32x4 __attribute__((ext_vector_type(4)));

__device__ __forceinline__ u16 f2bf(float f) {
    uint32_t u = __builtin_bit_cast(uint32_t, f);
    uint32_t r = (u + 0x7FFFu + ((u >> 16) & 1u)) >> 16;   // RNE
    return (u16)r;
}

// ---------------- weight prep: Wc[o][k] bf16 (pre-swizzled) --------------------
__global__ void prep_w_kernel(const float* __restrict__ bw,
                              const float* __restrict__ sw,
                              const float* __restrict__ sc,
                              u16* __restrict__ Wc) {
    int idx = blockIdx.x * 256 + threadIdx.x;      // (o,i), 512*512 threads
    int o = idx >> 9;
    int i = idx & 511;
    int swz = o & 7;
    Wc[(size_t)o * KDIM + (i ^ (swz << 3))] = f2bf(bw[idx]);
    float s = sc[idx];
    const float4* sp = reinterpret_cast<const float4*>(sw + (size_t)idx * 8);
    float4 a = sp[0];
    float4 b = sp[1];
    union { u16 us[8]; uint4 v; } pk;
    pk.us[0] = f2bf(a.x * s); pk.us[1] = f2bf(a.y * s);
    pk.us[2] = f2bf(a.z * s); pk.us[3] = f2bf(a.w * s);
    pk.us[4] = f2bf(b.x * s); pk.us[5] = f2bf(b.y * s);
    pk.us[6] = f2bf(b.z * s); pk.us[7] = f2bf(b.w * s);
    *reinterpret_cast<uint4*>(Wc + (size_t)o * KDIM + IN_F + (size_t)(i ^ swz) * 8) = pk.v;
}

// ---------------- activation prep: Act[b][*] bf16 (pre-swizzled) ---------------
// Uniform knots t_j = -2.2 + 0.4*j; x in [t_2, t_9) after clipping.
__global__ void prep_x_kernel(const float* __restrict__ x,
                              u16* __restrict__ Act) {
    int idx = blockIdx.x * 256 + threadIdx.x;      // (b,i), BATCH*IN_F threads
    int b = idx >> 9;
    int i = idx & 511;
    int swz = b & 7;
    float v = x[idx];
    if (v != v) v = 0.0f;                          // nan -> 0
    v = fminf(fmaxf(v, -6.0f), 6.0f);              // also folds +-inf
    v = fminf(fmaxf(v, -1.1f), 1.1f);              // grid clamp
    float s = v / (1.0f + __expf(-v));
    Act[(size_t)b * KDIM + (i ^ (swz << 3))] = f2bf(s);

    float t = (v + 2.2f) * 2.5f;                   // (v - t0)/h, h=0.4
    int m = (int)floorf(t);
    m = min(max(m, 2), 8);
    float u = t - (float)m;
    float u2 = u * u;
    float u3 = u2 * u;
    float p0 = u3 * (1.0f / 6.0f);
    float p1 = (1.0f + 3.0f * u + 3.0f * u2 - 3.0f * u3) * (1.0f / 6.0f);
    float p2 = (4.0f - 6.0f * u2 + 3.0f * u3) * (1.0f / 6.0f);
    float w1 = 1.0f - u;
    float p3 = w1 * w1 * w1 * (1.0f / 6.0f);

    union { u16 us[8]; uint4 v4; } pk;
    #pragma unroll
    for (int g = 0; g < 8; ++g) {
        int j = m - g;
        float r = 0.0f;
        r = (j == 0) ? p0 : r;
        r = (j == 1) ? p1 : r;
        r = (j == 2) ? p2 : r;
        r = (j == 3) ? p3 : r;
        pk.us[g] = f2bf(r);
    }
    *reinterpret_cast<uint4*>(Act + (size_t)b * KDIM + IN_F + (size_t)(i ^ swz) * 8) = pk.v4;
}

// ---------------- GEMM: C(16384x512) = Act(16384x4608) @ Wc(512x4608)^T --------
extern __shared__ u16 Sm[];

__global__ __launch_bounds__(512, 2) void gemm_kernel(const u16* __restrict__ A,
                                                      const u16* __restrict__ Bw,
                                                      float* __restrict__ C) {
    const int tid  = threadIdx.x;
    const int w    = tid >> 6;          // wave 0..7
    const int lane = tid & 63;

    // XCD-bijective swizzle, nwg = 256 (%8 == 0); A panels shared within an XCD
    const int bid = blockIdx.x;
    const int wg  = (bid & 7) * 32 + (bid >> 3);
    const int bm0 = (wg >> 2) * BM;     // 64 M-blocks
    const int bn0 = (wg & 3) * BN;      // 4 N-blocks

    const int wr = (w >> 1) * 64;       // 4 M-waves
    const int wc = (w & 1) * 64;        // 2 N-waves

    const int rA   = lane & 15;
    const int sK   = (rA & 7) << 3;     // ds_read column swizzle (elements)
    const int kgrp = (lane >> 4) * 8;

    f32x4 acc[4][4] = {};

    auto stageA = [&](u16* dst, int kt, int c) {
        int off = tid * 8 + c * 4096;
        int row = off >> 6, col = off & 63;
        const u16* g = A + (size_t)(bm0 + row) * KDIM + kt * BK + col;
        __builtin_amdgcn_global_load_lds(
            (const __attribute__((address_space(1))) uint32_t*)g,
            (__attribute__((address_space(3))) uint32_t*)(dst + off), 16, 0, 0);
    };
    auto stageB = [&](u16* dst, int kt, int c) {
        int off = tid * 8 + c * 4096;
        int row = off >> 6, col = off & 63;
        const u16* g = Bw + (size_t)(bn0 + row) * KDIM + kt * BK + col;
        __builtin_amdgcn_global_load_lds(
            (const __attribute__((address_space(1))) uint32_t*)g,
            (__attribute__((address_space(3))) uint32_t*)(dst + A_EL + off), 16, 0, 0);
    };

    // prologue: stage tiles 0 and 1 into ring bufs 0,1 (6 loads each)
    {
        u16* b0 = Sm;
        stageA(b0, 0, 0); stageA(b0, 0, 1); stageA(b0, 0, 2); stageA(b0, 0, 3);
        stageB(b0, 0, 0); stageB(b0, 0, 1);
        u16* b1 = Sm + T_EL;
        stageA(b1, 1, 0); stageA(b1, 1, 1); stageA(b1, 1, 2); stageA(b1, 1, 3);
        stageB(b1, 1, 0); stageB(b1, 1, 1);
    }
    asm volatile("s_waitcnt vmcnt(6)" ::: "memory");   // tile 0 landed
    __builtin_amdgcn_s_barrier();                      // visible to all waves

// One phase: early frag reads + partial next-next-tile staging -> barrier ->
// MFMA cluster -> (optional vmcnt before) end barrier.
#define PHASE(KK, STAGESTMT, ENDWAIT) do {                                          \
    const int kc = ((KK) * 32 + kgrp) ^ sK;                                         \
    s16x8 af0 = *reinterpret_cast<const s16x8*>(&AsR[(wr +  0 + rA) * BK + kc]);    \
    s16x8 af1 = *reinterpret_cast<const s16x8*>(&AsR[(wr + 16 + rA) * BK + kc]);    \
    s16x8 af2 = *reinterpret_cast<const s16x8*>(&AsR[(wr + 32 + rA) * BK + kc]);    \
    s16x8 af3 = *reinterpret_cast<const s16x8*>(&AsR[(wr + 48 + rA) * BK + kc]);    \
    s16x8 bf0 = *reinterpret_cast<const s16x8*>(&BsR[(wc +  0 + rA) * BK + kc]);    \
    s16x8 bf1 = *reinterpret_cast<const s16x8*>(&BsR[(wc + 16 + rA) * BK + kc]);    \
    s16x8 bf2 = *reinterpret_cast<const s16x8*>(&BsR[(wc + 32 + rA) * BK + kc]);    \
    s16x8 bf3 = *reinterpret_cast<const s16x8*>(&BsR[(wc + 48 + rA) * BK + kc]);    \
    STAGESTMT;                                                                      \
    __builtin_amdgcn_s_barrier();                                                   \
    __builtin_amdgcn_s_setprio(1);                                                  \
    acc[0][0] = __builtin_amdgcn_mfma_f32_16x16x32_bf16(af0, bf0, acc[0][0], 0,0,0); \
    acc[0][1] = __builtin_amdgcn_mfma_f32_16x16x32_bf16(af0, bf1, acc[0][1], 0,0,0); \
    acc[0][2] = __builtin_amdgcn_mfma_f32_16x16x32_bf16(af0, bf2, acc[0][2], 0,0,0); \
    acc[0][3] = __builtin_amdgcn_mfma_f32_16x16x32_bf16(af0, bf3, acc[0][3], 0,0,0); \
    acc[1][0] = __builtin_amdgcn_mfma_f32_16x16x32_bf16(af1, bf0, acc[1][0], 0,0,0); \
    acc[1][1] = __builtin_amdgcn_mfma_f32_16x16x32_bf16(af1, bf1, acc[1][1], 0,0,0); \
    acc[1][2] = __builtin_amdgcn_mfma_f32_16x16x32_bf16(af1, bf2, acc[1][2], 0,0,0); \
    acc[1][3] = __builtin_amdgcn_mfma_f32_16x16x32_bf16(af1, bf3, acc[1][3], 0,0,0); \
    acc[2][0] = __builtin_amdgcn_mfma_f32_16x16x32_bf16(af2, bf0, acc[2][0], 0,0,0); \
    acc[2][1] = __builtin_amdgcn_mfma_f32_16x16x32_bf16(af2, bf1, acc[2][1], 0,0,0); \
    acc[2][2] = __builtin_amdgcn_mfma_f32_16x16x32_bf16(af2, bf2, acc[2][2], 0,0,0); \
    acc[2][3] = __builtin_amdgcn_mfma_f32_16x16x32_bf16(af2, bf3, acc[2][3], 0,0,0); \
    acc[3][0] = __builtin_amdgcn_mfma_f32_16x16x32_bf16(af3, bf0, acc[3][0], 0,0,0); \
    acc[3][1] = __builtin_amdgcn_mfma_f32_16x16x32_bf16(af3, bf1, acc[3][1], 0,0,0); \
    acc[3][2] = __builtin_amdgcn_mfma_f32_16x16x32_bf16(af3, bf2, acc[3][2], 0,0,0); \
    acc[3][3] = __builtin_amdgcn_mfma_f32_16x16x32_bf16(af3, bf3, acc[3][3], 0,0,0); \
    __builtin_amdgcn_s_setprio(0);                                                  \
    ENDWAIT;                                                                        \
    __builtin_amdgcn_s_barrier();                                                   \
} while (0)

    int rb = 0, wb = 2;
    for (int t = 0; t < NT; ++t) {
        const u16* AsR = Sm + rb * T_EL;
        const u16* BsR = AsR + A_EL;
        u16* W_ = Sm + wb * T_EL;
        const bool pf = (t + 2 < NT);

        // phase alpha: kk=0, stage 3 loads of tile t+2
        PHASE(0,
              if (pf) { stageA(W_, t + 2, 0); stageA(W_, t + 2, 1); stageB(W_, t + 2, 0); },
              );
        // phase beta: kk=1, stage remaining 3; drain tile t+1 before end barrier
        PHASE(1,
              if (pf) { stageA(W_, t + 2, 2); stageA(W_, t + 2, 3); stageB(W_, t + 2, 1); },
              if (pf)              { asm volatile("s_waitcnt vmcnt(6)" ::: "memory"); }
              else if (t + 1 < NT) { asm volatile("s_waitcnt vmcnt(0)" ::: "memory"); });

        rb = (rb == 2) ? 0 : rb + 1;
        wb = (wb == 2) ? 0 : wb + 1;
    }
#undef PHASE

    // epilogue: C/D layout col = lane&15, row = (lane>>4)*4 + reg
    const int rq = lane >> 4;
    const int cn = lane & 15;
    #pragma unroll
    for (int am = 0; am < 4; ++am) {
        #pragma unroll
        for (int an = 0; an < 4; ++an) {
            const int row0 = bm0 + wr + am * 16 + rq * 4;
            const int col  = bn0 + wc + an * 16 + cn;
            float* cp = C + (size_t)row0 * OUT_F + col;
            cp[0 * OUT_F] = acc[am][an][0];
            cp[1 * OUT_F] = acc[am][an][1];
            cp[2 * OUT_F] = acc[am][an][2];
            cp[3 * OUT_F] = acc[am][an][3];
        }
    }
}

extern "C" void kernel_launch(void* const* d_in, const int* in_sizes, int n_in,
                              void* d_out, int out_size, void* d_ws, size_t ws_size,
                              hipStream_t stream) {
    const float* x  = (const float*)d_in[0];
    const float* bw = (const float*)d_in[1];
    const float* sw = (const float*)d_in[2];
    const float* sc = (const float*)d_in[3];
    // d_in[4] (grid) unused: uniform knots by construction

    u16* Wc  = (u16*)d_ws;                         // 512*4608*2   = 4.7 MB
    u16* Act = Wc + (size_t)OUT_F * KDIM;          // 16384*4608*2 = 151 MB

    hipFuncSetAttribute((const void*)gemm_kernel,
                        hipFuncAttributeMaxDynamicSharedMemorySize, LDS_BYTES);

    prep_w_kernel<<<(OUT_F * IN_F) / 256, 256, 0, stream>>>(bw, sw, sc, Wc);
    prep_x_kernel<<<(BATCH * IN_F) / 256, 256, 0, stream>>>(x, Act);
    gemm_kernel<<<(BATCH / BM) * (OUT_F / BN), 512, LDS_BYTES, stream>>>(Act, Wc, (float*)d_out);
}

// Round 11
// 111.393 us; speedup vs baseline: 1.0469x; 1.0469x over previous
//
#include <hip/hip_runtime.h>
#include <stdint.h>

// KANLinear: y = silu(x) @ W_b^T + einsum('big,oig->bo', bases(x), W_s * scaler)
// Act = [silu(x) | bases] (B x 4608) bf16, Wc = [W_b | W_s*scaler] (512 x 4608) bf16,
// both pre-XOR-swizzled per 64-elem K-group; one bf16 MFMA GEMM.
// R10: R4 skeleton (2-barrier dbuf, vmcnt(8), 2 blocks/CU) with per-wave 128x64
// output (8x4 frags) + split-K wave pairs (4 waves = 2 N-pos x 2 kk-halves).
// LDS read traffic per block-tile 64KB -> 48KB (demand at MFMA floor 105 -> 79
// B/cyc, below the ~85 B/cyc ds_read_b128 rate). Epilogue reduces kh pairs via LDS.

#define IN_F   512
#define OUT_F  512
#define KDIM   4608
#define BATCH  16384

#define BM 128
#define BN 128
#define BK 64
#define NT (KDIM / BK)                 // 72
#define A_ELEMS (BM * BK)              // 8192 elems
#define B_ELEMS (BN * BK)              // 8192 elems
#define TILE_ELEMS (A_ELEMS + B_ELEMS) // 16384 elems = 32 KiB

typedef unsigned short u16;
typedef short s16x8 __attribute__((ext_vector_type(8)));
typedef float f32x4 __attribute__((ext_vector_type(4)));

__device__ __forceinline__ u16 f2bf(float f) {
    uint32_t u = __builtin_bit_cast(uint32_t, f);
    uint32_t r = (u + 0x7FFFu + ((u >> 16) & 1u)) >> 16;   // RNE
    return (u16)r;
}

// ---------------- weight prep: Wc[o][k] bf16 (pre-swizzled) --------------------
__global__ void prep_w_kernel(const float* __restrict__ bw,
                              const float* __restrict__ sw,
                              const float* __restrict__ sc,
                              u16* __restrict__ Wc) {
    int idx = blockIdx.x * 256 + threadIdx.x;      // (o,i), 512*512 threads
    int o = idx >> 9;
    int i = idx & 511;
    int swz = o & 7;
    Wc[(size_t)o * KDIM + (i ^ (swz << 3))] = f2bf(bw[idx]);
    float s = sc[idx];
    const float4* sp = reinterpret_cast<const float4*>(sw + (size_t)idx * 8);
    float4 a = sp[0];
    float4 b = sp[1];
    union { u16 us[8]; uint4 v; } pk;
    pk.us[0] = f2bf(a.x * s); pk.us[1] = f2bf(a.y * s);
    pk.us[2] = f2bf(a.z * s); pk.us[3] = f2bf(a.w * s);
    pk.us[4] = f2bf(b.x * s); pk.us[5] = f2bf(b.y * s);
    pk.us[6] = f2bf(b.z * s); pk.us[7] = f2bf(b.w * s);
    *reinterpret_cast<uint4*>(Wc + (size_t)o * KDIM + IN_F + (size_t)(i ^ swz) * 8) = pk.v;
}

// ---------------- activation prep: Act[b][*] bf16 (pre-swizzled) ---------------
// Uniform knots t_j = -2.2 + 0.4*j; x in [t_2, t_9) after clipping.
__global__ void prep_x_kernel(const float* __restrict__ x,
                              u16* __restrict__ Act) {
    int idx = blockIdx.x * 256 + threadIdx.x;      // (b,i), BATCH*IN_F threads
    int b = idx >> 9;
    int i = idx & 511;
    int swz = b & 7;
    float v = x[idx];
    if (v != v) v = 0.0f;                          // nan -> 0
    v = fminf(fmaxf(v, -6.0f), 6.0f);              // also folds +-inf
    v = fminf(fmaxf(v, -1.1f), 1.1f);              // grid clamp
    float s = v / (1.0f + __expf(-v));
    Act[(size_t)b * KDIM + (i ^ (swz << 3))] = f2bf(s);

    float t = (v + 2.2f) * 2.5f;                   // (v - t0)/h, h=0.4
    int m = (int)floorf(t);
    m = min(max(m, 2), 8);
    float u = t - (float)m;
    float u2 = u * u;
    float u3 = u2 * u;
    float p0 = u3 * (1.0f / 6.0f);
    float p1 = (1.0f + 3.0f * u + 3.0f * u2 - 3.0f * u3) * (1.0f / 6.0f);
    float p2 = (4.0f - 6.0f * u2 + 3.0f * u3) * (1.0f / 6.0f);
    float w1 = 1.0f - u;
    float p3 = w1 * w1 * w1 * (1.0f / 6.0f);

    union { u16 us[8]; uint4 v4; } pk;
    #pragma unroll
    for (int g = 0; g < 8; ++g) {
        int j = m - g;
        float r = 0.0f;
        r = (j == 0) ? p0 : r;
        r = (j == 1) ? p1 : r;
        r = (j == 2) ? p2 : r;
        r = (j == 3) ? p3 : r;
        pk.us[g] = f2bf(r);
    }
    *reinterpret_cast<uint4*>(Act + (size_t)b * KDIM + IN_F + (size_t)(i ^ swz) * 8) = pk.v4;
}

// ---------------- GEMM: C(16384x512) = Act(16384x4608) @ Wc(512x4608)^T --------
__global__ __launch_bounds__(256, 2) void gemm_kernel(const u16* __restrict__ A,
                                                      const u16* __restrict__ Bw,
                                                      float* __restrict__ C) {
    __shared__ __align__(16) u16 Sm[2 * TILE_ELEMS];   // 64 KiB

    const int tid  = threadIdx.x;
    const int w    = tid >> 6;
    const int lane = tid & 63;

    // XCD-bijective swizzle, nwg = 512 (%8 == 0); 4 N-siblings adjacent per XCD
    const int bid = blockIdx.x;
    const int wg  = (bid & 7) * 64 + (bid >> 3);
    const int bm0 = (wg >> 2) * BM;
    const int bn0 = (wg & 3) * BN;

    const int wc = (w >> 1) * 64;       // 2 N-positions
    const int kh = w & 1;               // split-K half

    const int rA   = lane & 15;
    const int sK   = (rA & 7) << 3;     // ds_read column swizzle (elements)
    const int kgrp = (lane >> 4) * 8;
    const int kc   = (kh * 32 + kgrp) ^ sK;   // constant per wave

    f32x4 acc[8][4] = {};

    auto stage = [&](u16* dst, int kt) {
        #pragma unroll
        for (int c = 0; c < 4; ++c) {
            int off = tid * 8 + c * 2048;
            int row = off >> 6, col = off & 63;
            const u16* ga = A  + (size_t)(bm0 + row) * KDIM + kt * BK + col;
            const u16* gb = Bw + (size_t)(bn0 + row) * KDIM + kt * BK + col;
            __builtin_amdgcn_global_load_lds(
                (const __attribute__((address_space(1))) uint32_t*)ga,
                (__attribute__((address_space(3))) uint32_t*)(dst + off), 16, 0, 0);
            __builtin_amdgcn_global_load_lds(
                (const __attribute__((address_space(1))) uint32_t*)gb,
                (__attribute__((address_space(3))) uint32_t*)(dst + A_ELEMS + off), 16, 0, 0);
        }
    };

    stage(Sm, 0);                        // prologue

    int cur = 0;
    for (int t = 0; t < NT; ++t) {
        __builtin_amdgcn_s_barrier();    // all waves done reading buf[cur^1]
        if (t + 1 < NT) {
            stage(Sm + (cur ^ 1) * TILE_ELEMS, t + 1);
            asm volatile("s_waitcnt vmcnt(8)" ::: "memory");   // tile t landed
        } else {
            asm volatile("s_waitcnt vmcnt(0)" ::: "memory");
        }
        __builtin_amdgcn_s_barrier();    // whole tile t visible to all waves

        const u16* As_ = Sm + cur * TILE_ELEMS;
        const u16* Bs_ = As_ + A_ELEMS;

        s16x8 af[8], bf[4];
        #pragma unroll
        for (int m = 0; m < 8; ++m)
            af[m] = *reinterpret_cast<const s16x8*>(&As_[(m * 16 + rA) * BK + kc]);
        #pragma unroll
        for (int n = 0; n < 4; ++n)
            bf[n] = *reinterpret_cast<const s16x8*>(&Bs_[(wc + n * 16 + rA) * BK + kc]);

        __builtin_amdgcn_s_setprio(1);
        #pragma unroll
        for (int m = 0; m < 8; ++m)
            #pragma unroll
            for (int n = 0; n < 4; ++n)
                acc[m][n] = __builtin_amdgcn_mfma_f32_16x16x32_bf16(
                    af[m], bf[n], acc[m][n], 0, 0, 0);
        __builtin_amdgcn_s_setprio(0);
        cur ^= 1;
    }

    // ---- split-K reduce: kh=1 waves dump acc to LDS, kh=0 waves add ----
    __builtin_amdgcn_s_barrier();                    // LDS free for reuse
    float* red = reinterpret_cast<float*>(Sm);       // 16384 floats = 64 KiB
    const int half = (w >> 1) * 8192;                // per N-position region
    if (kh == 1) {
        #pragma unroll
        for (int m = 0; m < 8; ++m)
            #pragma unroll
            for (int n = 0; n < 4; ++n)
                *reinterpret_cast<f32x4*>(&red[half + ((m * 4 + n) * 64 + lane) * 4]) = acc[m][n];
    }
    __builtin_amdgcn_s_barrier();

    if (kh == 0) {
        const int rq = lane >> 4;
        const int cn = lane & 15;
        #pragma unroll
        for (int m = 0; m < 8; ++m) {
            #pragma unroll
            for (int n = 0; n < 4; ++n) {
                f32x4 o = *reinterpret_cast<const f32x4*>(&red[half + ((m * 4 + n) * 64 + lane) * 4]);
                f32x4 r = acc[m][n] + o;
                // C/D layout: col = lane&15, row = (lane>>4)*4 + reg
                const int row0 = bm0 + m * 16 + rq * 4;
                const int col  = bn0 + wc + n * 16 + cn;
                float* cp = C + (size_t)row0 * OUT_F + col;
                cp[0 * OUT_F] = r[0];
                cp[1 * OUT_F] = r[1];
                cp[2 * OUT_F] = r[2];
                cp[3 * OUT_F] = r[3];
            }
        }
    }
}

extern "C" void kernel_launch(void* const* d_in, const int* in_sizes, int n_in,
                              void* d_out, int out_size, void* d_ws, size_t ws_size,
                              hipStream_t stream) {
    const float* x  = (const float*)d_in[0];
    const float* bw = (const float*)d_in[1];
    const float* sw = (const float*)d_in[2];
    const float* sc = (const float*)d_in[3];
    // d_in[4] (grid) unused: uniform knots by construction

    u16* Wc  = (u16*)d_ws;                         // 512*4608*2   = 4.7 MB
    u16* Act = Wc + (size_t)OUT_F * KDIM;          // 16384*4608*2 = 151 MB

    prep_w_kernel<<<(OUT_F * IN_F) / 256, 256, 0, stream>>>(bw, sw, sc, Wc);
    prep_x_kernel<<<(BATCH * IN_F) / 256, 256, 0, stream>>>(x, Act);
    gemm_kernel<<<(BATCH / BM) * (OUT_F / BN), 256, 0, stream>>>(Act, Wc, (float*)d_out);
}

// Round 12
// 94.146 us; speedup vs baseline: 1.2386x; 1.1832x over previous
//
#include <hip/hip_runtime.h>
#include <stdint.h>

// KANLinear: y = silu(x) @ W_b^T + einsum('big,oig->bo', bases(x), W_s * scaler)
// R11: mixed-precision GEMM. Silu section (K=512) bf16 MFMA; spline section
// (K=4096, 89% of FLOPs) int8 MFMA (mfma_i32_16x16x64_i8, 2x rate, exact i32
// accum). Bases quantized with fixed scale 190.5 (bases <= 2/3); weights with
// per-output-row scale 127/max. Epilogue: y = acc_f32 + acc_i32 * EpiS[col].
// GEMM skeleton = R4 (2-barrier dbuf, counted vmcnt, 4 waves, 2 blocks/CU).
// i8 LDS tiles have 64B rows -> 2 lanes/bank (free), no swizzle needed.

#define IN_F   512
#define OUT_F  512
#define KS     4096                    // spline K
#define BATCH  16384

#define BM 128
#define BN 128
#define BK 64
#define NT_BF 8                        // bf16 K-tiles (silu)
#define NT_I8 64                       // i8 K-tiles (spline)
#define A_ELEMS (BM * BK)              // 8192 u16
#define TILE_U16 (2 * A_ELEMS)         // 16384 u16 = 32 KiB (bf16 A+B tile)
#define TILE_I8  16384                 // bytes (i8 A 8K + B 8K)

typedef unsigned short u16;
typedef unsigned char u8;
typedef short s16x8 __attribute__((ext_vector_type(8)));
typedef int   i32x4 __attribute__((ext_vector_type(4)));
typedef float f32x4 __attribute__((ext_vector_type(4)));

__device__ __forceinline__ u16 f2bf(float f) {
    uint32_t u = __builtin_bit_cast(uint32_t, f);
    uint32_t r = (u + 0x7FFFu + ((u >> 16) & 1u)) >> 16;   // RNE
    return (u16)r;
}

__device__ __forceinline__ float cleanx(float v) {
    if (v != v) v = 0.0f;
    v = fminf(fmaxf(v, -6.0f), 6.0f);
    return fminf(fmaxf(v, -1.1f), 1.1f);
}

// ---------------- prep: W_b -> bf16 [512][512], pre-XOR-swizzled --------------
__global__ void prep_wb_kernel(const float* __restrict__ bw, u16* __restrict__ Wb) {
    int idx = blockIdx.x * 256 + threadIdx.x;      // 512*512
    int o = idx >> 9;
    int i = idx & 511;
    Wb[(size_t)o * IN_F + (i ^ ((o & 7) << 3))] = f2bf(bw[idx]);
}

// ---------------- prep: W_s*scaler -> i8 [512][4096] + per-row epi scale -------
__global__ __launch_bounds__(256) void prep_ws_kernel(const float* __restrict__ sw,
                                                      const float* __restrict__ sc,
                                                      char* __restrict__ Ws,
                                                      float* __restrict__ EpiS) {
    const int o = blockIdx.x;                      // 512 blocks
    const int t = threadIdx.x;                     // 256
    const float* wrow = sw + (size_t)o * KS;
    const float* srow = sc + (size_t)o * IN_F;

    float vals[16];
    float mx = 0.0f;
    #pragma unroll
    for (int e = 0; e < 16; ++e) {
        int k = t * 16 + e;
        float v = wrow[k] * srow[k >> 3];
        vals[e] = v;
        mx = fmaxf(mx, fabsf(v));
    }
    #pragma unroll
    for (int off = 32; off >= 1; off >>= 1)
        mx = fmaxf(mx, __shfl_xor(mx, off));
    __shared__ float wmx[4];
    if ((t & 63) == 0) wmx[t >> 6] = mx;
    __syncthreads();
    float gmx = fmaxf(fmaxf(wmx[0], wmx[1]), fmaxf(wmx[2], wmx[3]));
    float scale = 127.0f / fmaxf(gmx, 1e-20f);
    if (t == 0) EpiS[o] = 1.0f / (190.5f * scale);

    union { char q[16]; uint4 v; } pk;
    #pragma unroll
    for (int e = 0; e < 16; ++e) {
        float q = vals[e] * scale;
        q = fminf(fmaxf(q, -127.0f), 127.0f);
        pk.q[e] = (char)__float2int_rn(q);
    }
    *reinterpret_cast<uint4*>(Ws + (size_t)o * KS + t * 16) = pk.v;
}

// ---------------- prep: x -> Act_s (silu bf16, swizzled) + Act_sp (bases i8) ---
// Uniform knots t_j = -2.2 + 0.4*j; x in [t_2, t_9) after clipping.
__global__ void prep_x_kernel(const float* __restrict__ x,
                              u16* __restrict__ Act_s,
                              u8* __restrict__ Act_sp) {
    int idx = blockIdx.x * 256 + threadIdx.x;      // BATCH*IN_F
    int b = idx >> 9;
    int i = idx & 511;
    float v = cleanx(x[idx]);

    float s = v / (1.0f + __expf(-v));
    Act_s[(size_t)b * IN_F + (i ^ ((b & 7) << 3))] = f2bf(s);

    float t = (v + 2.2f) * 2.5f;
    int m = (int)floorf(t);
    m = min(max(m, 2), 8);
    float u = t - (float)m;
    float u2 = u * u;
    float u3 = u2 * u;
    float p0 = u3 * (1.0f / 6.0f);
    float p1 = (1.0f + 3.0f * u + 3.0f * u2 - 3.0f * u3) * (1.0f / 6.0f);
    float p2 = (4.0f - 6.0f * u2 + 3.0f * u3) * (1.0f / 6.0f);
    float w1 = 1.0f - u;
    float p3 = w1 * w1 * w1 * (1.0f / 6.0f);

    union { u8 q[8]; uint2 v2; } pk;
    #pragma unroll
    for (int g = 0; g < 8; ++g) {
        int j = m - g;
        float r = 0.0f;
        r = (j == 0) ? p0 : r;
        r = (j == 1) ? p1 : r;
        r = (j == 2) ? p2 : r;
        r = (j == 3) ? p3 : r;
        pk.q[g] = (u8)(r * 190.5f + 0.5f);         // bases >= 0, <= 2/3 -> <= 127
    }
    *reinterpret_cast<uint2*>(Act_sp + (size_t)b * KS + i * 8) = pk.v2;
}

// ---------------- GEMM: C = Act_s @ Wb^T (bf16) + scaled(Act_sp @ Ws^T) (i8) ---
__global__ __launch_bounds__(256, 2) void gemm_kernel(const u16* __restrict__ As_g,
                                                      const u16* __restrict__ Wb,
                                                      const u8*  __restrict__ Asp_g,
                                                      const char* __restrict__ Ws,
                                                      const float* __restrict__ EpiS,
                                                      float* __restrict__ C) {
    __shared__ __align__(16) u16 Sm[2 * TILE_U16];     // 64 KiB

    const int tid  = threadIdx.x;
    const int w    = tid >> 6;
    const int lane = tid & 63;

    // XCD-bijective swizzle, nwg = 512; 4 N-siblings adjacent per XCD
    const int bid = blockIdx.x;
    const int wg  = (bid & 7) * 64 + (bid >> 3);
    const int bm0 = (wg >> 2) * BM;
    const int bn0 = (wg & 3) * BN;

    const int wr = (w >> 1) * 64;       // 2 M-waves
    const int wc = (w & 1) * 64;        // 2 N-waves

    const int rA   = lane & 15;
    const int sK   = (rA & 7) << 3;     // bf16 read-side swizzle
    const int kgrp = (lane >> 4) * 8;   // bf16 k-group
    const int kci8 = (lane >> 4) * 16;  // i8 k-group (bytes)

    f32x4 acc[4][4] = {};
    i32x4 acci[4][4] = {};

    // ---------------- loop A: bf16 silu section (8 tiles) ----------------
    auto stage_bf = [&](u16* dst, int kt) {
        #pragma unroll
        for (int c = 0; c < 4; ++c) {
            int off = tid * 8 + c * 2048;
            int row = off >> 6, col = off & 63;
            const u16* ga = As_g + (size_t)(bm0 + row) * IN_F + kt * BK + col;
            const u16* gb = Wb   + (size_t)(bn0 + row) * IN_F + kt * BK + col;
            __builtin_amdgcn_global_load_lds(
                (const __attribute__((address_space(1))) uint32_t*)ga,
                (__attribute__((address_space(3))) uint32_t*)(dst + off), 16, 0, 0);
            __builtin_amdgcn_global_load_lds(
                (const __attribute__((address_space(1))) uint32_t*)gb,
                (__attribute__((address_space(3))) uint32_t*)(dst + A_ELEMS + off), 16, 0, 0);
        }
    };

    stage_bf(Sm, 0);
    int cur = 0;
    for (int t = 0; t < NT_BF; ++t) {
        __builtin_amdgcn_s_barrier();
        if (t + 1 < NT_BF) {
            stage_bf(Sm + (cur ^ 1) * TILE_U16, t + 1);
            asm volatile("s_waitcnt vmcnt(8)" ::: "memory");
        } else {
            asm volatile("s_waitcnt vmcnt(0)" ::: "memory");
        }
        __builtin_amdgcn_s_barrier();

        const u16* As_ = Sm + cur * TILE_U16;
        const u16* Bs_ = As_ + A_ELEMS;
        s16x8 af[4][2], bf[2][4];
        #pragma unroll
        for (int kk = 0; kk < 2; ++kk) {
            const int kc = (kk * 32 + kgrp) ^ sK;
            #pragma unroll
            for (int m = 0; m < 4; ++m)
                af[m][kk] = *reinterpret_cast<const s16x8*>(&As_[(wr + m * 16 + rA) * BK + kc]);
            #pragma unroll
            for (int n = 0; n < 4; ++n)
                bf[kk][n] = *reinterpret_cast<const s16x8*>(&Bs_[(wc + n * 16 + rA) * BK + kc]);
        }
        __builtin_amdgcn_s_setprio(1);
        #pragma unroll
        for (int kk = 0; kk < 2; ++kk)
            #pragma unroll
            for (int m = 0; m < 4; ++m)
                #pragma unroll
                for (int n = 0; n < 4; ++n)
                    acc[m][n] = __builtin_amdgcn_mfma_f32_16x16x32_bf16(
                        af[m][kk], bf[kk][n], acc[m][n], 0, 0, 0);
        __builtin_amdgcn_s_setprio(0);
        cur ^= 1;
    }

    // ---------------- loop B: i8 spline section (64 tiles) ----------------
    u8* SmB = reinterpret_cast<u8*>(Sm);
    auto stage_i8 = [&](u8* dst, int kt) {
        #pragma unroll
        for (int c = 0; c < 2; ++c) {
            int off = tid * 16 + c * 4096;
            int row = off >> 6, col = off & 63;
            const u8* ga = Asp_g + (size_t)(bm0 + row) * KS + kt * BK + col;
            const u8* gb = (const u8*)Ws + (size_t)(bn0 + row) * KS + kt * BK + col;
            __builtin_amdgcn_global_load_lds(
                (const __attribute__((address_space(1))) uint32_t*)ga,
                (__attribute__((address_space(3))) uint32_t*)(dst + off), 16, 0, 0);
            __builtin_amdgcn_global_load_lds(
                (const __attribute__((address_space(1))) uint32_t*)gb,
                (__attribute__((address_space(3))) uint32_t*)(dst + 8192 + off), 16, 0, 0);
        }
    };

    stage_i8(SmB, 0);                   // safe: writes buf0 region, loop A done
    cur = 0;
    for (int t = 0; t < NT_I8; ++t) {
        __builtin_amdgcn_s_barrier();
        if (t + 1 < NT_I8) {
            stage_i8(SmB + (cur ^ 1) * TILE_I8, t + 1);
            asm volatile("s_waitcnt vmcnt(4)" ::: "memory");
        } else {
            asm volatile("s_waitcnt vmcnt(0)" ::: "memory");
        }
        __builtin_amdgcn_s_barrier();

        const u8* Aa = SmB + cur * TILE_I8;
        const u8* Bb = Aa + 8192;
        i32x4 af[4], bfr[4];
        #pragma unroll
        for (int m = 0; m < 4; ++m)
            af[m] = *reinterpret_cast<const i32x4*>(&Aa[(wr + m * 16 + rA) * BK + kci8]);
        #pragma unroll
        for (int n = 0; n < 4; ++n)
            bfr[n] = *reinterpret_cast<const i32x4*>(&Bb[(wc + n * 16 + rA) * BK + kci8]);

        __builtin_amdgcn_s_setprio(1);
        #pragma unroll
        for (int m = 0; m < 4; ++m)
            #pragma unroll
            for (int n = 0; n < 4; ++n)
                acci[m][n] = __builtin_amdgcn_mfma_i32_16x16x64_i8(
                    af[m], bfr[n], acci[m][n], 0, 0, 0);
        __builtin_amdgcn_s_setprio(0);
        cur ^= 1;
    }

    // epilogue: C/D layout col = lane&15, row = (lane>>4)*4 + reg
    const int rq = lane >> 4;
    const int cn = lane & 15;
    #pragma unroll
    for (int n = 0; n < 4; ++n) {
        const int col = bn0 + wc + n * 16 + cn;
        const float es = EpiS[col];
        #pragma unroll
        for (int m = 0; m < 4; ++m) {
            const int row0 = bm0 + wr + m * 16 + rq * 4;
            float* cp = C + (size_t)row0 * OUT_F + col;
            cp[0 * OUT_F] = acc[m][n][0] + (float)acci[m][n][0] * es;
            cp[1 * OUT_F] = acc[m][n][1] + (float)acci[m][n][1] * es;
            cp[2 * OUT_F] = acc[m][n][2] + (float)acci[m][n][2] * es;
            cp[3 * OUT_F] = acc[m][n][3] + (float)acci[m][n][3] * es;
        }
    }
}

extern "C" void kernel_launch(void* const* d_in, const int* in_sizes, int n_in,
                              void* d_out, int out_size, void* d_ws, size_t ws_size,
                              hipStream_t stream) {
    const float* x  = (const float*)d_in[0];
    const float* bw = (const float*)d_in[1];
    const float* sw = (const float*)d_in[2];
    const float* sc = (const float*)d_in[3];
    // d_in[4] (grid) unused: uniform knots by construction

    char* p = (char*)d_ws;
    u16*   Wb    = (u16*)p;                       p += (size_t)OUT_F * IN_F * 2;   // 0.5 MB
    char*  Ws    = p;                             p += (size_t)OUT_F * KS;         // 2 MB
    float* EpiS  = (float*)p;                     p += OUT_F * 4;
    u16*   Act_s = (u16*)p;                       p += (size_t)BATCH * IN_F * 2;   // 16.8 MB
    u8*    Act_sp= (u8*)p;                                                          // 67 MB

    prep_wb_kernel<<<(OUT_F * IN_F) / 256, 256, 0, stream>>>(bw, Wb);
    prep_ws_kernel<<<OUT_F, 256, 0, stream>>>(sw, sc, Ws, EpiS);
    prep_x_kernel<<<(BATCH * IN_F) / 256, 256, 0, stream>>>(x, Act_s, Act_sp);
    gemm_kernel<<<(BATCH / BM) * (OUT_F / BN), 256, 0, stream>>>(
        Act_s, Wb, Act_sp, Ws, EpiS, (float*)d_out);
}

// Round 13
// 82.709 us; speedup vs baseline: 1.4099x; 1.1383x over previous
//
#include <hip/hip_runtime.h>
#include <stdint.h>

// KANLinear: y = silu(x) @ W_b^T + einsum('big,oig->bo', bases(x), W_s * scaler)
// R12: R11 (mixed bf16 silu / i8 spline MFMA) with the i8 loop upgraded:
// BK=128 (32 tiles, 32 MFMA/tile - amortizes the per-tile stage+barrier stall)
// and 16B-chunk XOR swizzle (p ^= (row&7)<<4) pre-baked into Act_sp/Ws layout
// (global_load_lds is linear) + applied on ds_read -> conflict-free.
// Skeleton: 2-barrier dbuf, counted vmcnt, 4 waves, 64KB LDS, 2 blocks/CU.

#define IN_F   512
#define OUT_F  512
#define KS     4096                    // spline K (bytes per row of i8 Act)
#define BATCH  16384

#define BM 128
#define BN 128
#define BK 64                          // bf16 section K-tile
#define NT_BF 8                        // bf16 K-tiles (silu)
#define BKI 128                        // i8 section K-tile (bytes)
#define NT_I8 (KS / BKI)               // 32
#define A_ELEMS (BM * BK)              // 8192 u16
#define TILE_U16 (2 * A_ELEMS)         // 16384 u16 = 32 KiB (bf16 A+B tile)
#define A_I8 (BM * BKI)                // 16384 bytes
#define TILE_I8 (2 * A_I8)             // 32768 bytes (i8 A+B tile)

typedef unsigned short u16;
typedef unsigned char u8;
typedef short s16x8 __attribute__((ext_vector_type(8)));
typedef int   i32x4 __attribute__((ext_vector_type(4)));
typedef float f32x4 __attribute__((ext_vector_type(4)));

__device__ __forceinline__ u16 f2bf(float f) {
    uint32_t u = __builtin_bit_cast(uint32_t, f);
    uint32_t r = (u + 0x7FFFu + ((u >> 16) & 1u)) >> 16;   // RNE
    return (u16)r;
}

__device__ __forceinline__ float cleanx(float v) {
    if (v != v) v = 0.0f;
    v = fminf(fmaxf(v, -6.0f), 6.0f);
    return fminf(fmaxf(v, -1.1f), 1.1f);
}

// ---------------- prep: W_b -> bf16 [512][512], pre-XOR-swizzled --------------
__global__ void prep_wb_kernel(const float* __restrict__ bw, u16* __restrict__ Wb) {
    int idx = blockIdx.x * 256 + threadIdx.x;      // 512*512
    int o = idx >> 9;
    int i = idx & 511;
    Wb[(size_t)o * IN_F + (i ^ ((o & 7) << 3))] = f2bf(bw[idx]);
}

// ---------------- prep: W_s*scaler -> i8 [512][4096] (chunk-swizzled) ----------
__global__ __launch_bounds__(256) void prep_ws_kernel(const float* __restrict__ sw,
                                                      const float* __restrict__ sc,
                                                      char* __restrict__ Ws,
                                                      float* __restrict__ EpiS) {
    const int o = blockIdx.x;                      // 512 blocks
    const int t = threadIdx.x;                     // 256
    const float* wrow = sw + (size_t)o * KS;
    const float* srow = sc + (size_t)o * IN_F;

    float vals[16];
    float mx = 0.0f;
    #pragma unroll
    for (int e = 0; e < 16; ++e) {
        int k = t * 16 + e;
        float v = wrow[k] * srow[k >> 3];
        vals[e] = v;
        mx = fmaxf(mx, fabsf(v));
    }
    #pragma unroll
    for (int off = 32; off >= 1; off >>= 1)
        mx = fmaxf(mx, __shfl_xor(mx, off));
    __shared__ float wmx[4];
    if ((t & 63) == 0) wmx[t >> 6] = mx;
    __syncthreads();
    float gmx = fmaxf(fmaxf(wmx[0], wmx[1]), fmaxf(wmx[2], wmx[3]));
    float scale = 127.0f / fmaxf(gmx, 1e-20f);
    if (t == 0) EpiS[o] = 1.0f / (190.5f * scale);

    union { char q[16]; uint4 v; } pk;
    #pragma unroll
    for (int e = 0; e < 16; ++e) {
        float q = vals[e] * scale;
        q = fminf(fmaxf(q, -127.0f), 127.0f);
        pk.q[e] = (char)__float2int_rn(q);
    }
    // 16B-chunk XOR swizzle within each 128B K-segment (bits 4-6 of byte pos)
    int p = (t * 16) ^ ((o & 7) << 4);
    *reinterpret_cast<uint4*>(Ws + (size_t)o * KS + p) = pk.v;
}

// ---------------- prep: x -> Act_s (silu bf16, swz) + Act_sp (bases i8, swz) ---
// Uniform knots t_j = -2.2 + 0.4*j; x in [t_2, t_9) after clipping.
__global__ void prep_x_kernel(const float* __restrict__ x,
                              u16* __restrict__ Act_s,
                              u8* __restrict__ Act_sp) {
    int idx = blockIdx.x * 256 + threadIdx.x;      // BATCH*IN_F
    int b = idx >> 9;
    int i = idx & 511;
    float v = cleanx(x[idx]);

    float s = v / (1.0f + __expf(-v));
    Act_s[(size_t)b * IN_F + (i ^ ((b & 7) << 3))] = f2bf(s);

    float t = (v + 2.2f) * 2.5f;
    int m = (int)floorf(t);
    m = min(max(m, 2), 8);
    float u = t - (float)m;
    float u2 = u * u;
    float u3 = u2 * u;
    float p0 = u3 * (1.0f / 6.0f);
    float p1 = (1.0f + 3.0f * u + 3.0f * u2 - 3.0f * u3) * (1.0f / 6.0f);
    float p2 = (4.0f - 6.0f * u2 + 3.0f * u3) * (1.0f / 6.0f);
    float w1 = 1.0f - u;
    float p3 = w1 * w1 * w1 * (1.0f / 6.0f);

    union { u8 q[8]; uint2 v2; } pk;
    #pragma unroll
    for (int g = 0; g < 8; ++g) {
        int j = m - g;
        float r = 0.0f;
        r = (j == 0) ? p0 : r;
        r = (j == 1) ? p1 : r;
        r = (j == 2) ? p2 : r;
        r = (j == 3) ? p3 : r;
        pk.q[g] = (u8)(r * 190.5f + 0.5f);         // bases in [0, 2/3] -> <= 127
    }
    // byte pos i*8, chunk-swizzled within its 128B segment
    int p = (i * 8) ^ ((b & 7) << 4);
    *reinterpret_cast<uint2*>(Act_sp + (size_t)b * KS + p) = pk.v2;
}

// ---------------- GEMM: C = Act_s @ Wb^T (bf16) + scaled(Act_sp @ Ws^T) (i8) ---
__global__ __launch_bounds__(256, 2) void gemm_kernel(const u16* __restrict__ As_g,
                                                      const u16* __restrict__ Wb,
                                                      const u8*  __restrict__ Asp_g,
                                                      const char* __restrict__ Ws,
                                                      const float* __restrict__ EpiS,
                                                      float* __restrict__ C) {
    __shared__ __align__(16) u16 Sm[2 * TILE_U16];     // 64 KiB

    const int tid  = threadIdx.x;
    const int w    = tid >> 6;
    const int lane = tid & 63;

    // XCD-bijective swizzle, nwg = 512; 4 N-siblings adjacent per XCD
    const int bid = blockIdx.x;
    const int wg  = (bid & 7) * 64 + (bid >> 3);
    const int bm0 = (wg >> 2) * BM;
    const int bn0 = (wg & 3) * BN;

    const int wr = (w >> 1) * 64;       // 2 M-waves
    const int wc = (w & 1) * 64;        // 2 N-waves

    const int rA   = lane & 15;
    const int sK   = (rA & 7) << 3;     // bf16 read-side swizzle
    const int kgrp = (lane >> 4) * 8;   // bf16 k-group
    const int kg8  = (lane >> 4) * 16;  // i8 k-group (bytes)

    f32x4 acc[4][4] = {};
    i32x4 acci[4][4] = {};

    // ---------------- loop A: bf16 silu section (8 tiles) ----------------
    auto stage_bf = [&](u16* dst, int kt) {
        #pragma unroll
        for (int c = 0; c < 4; ++c) {
            int off = tid * 8 + c * 2048;
            int row = off >> 6, col = off & 63;
            const u16* ga = As_g + (size_t)(bm0 + row) * IN_F + kt * BK + col;
            const u16* gb = Wb   + (size_t)(bn0 + row) * IN_F + kt * BK + col;
            __builtin_amdgcn_global_load_lds(
                (const __attribute__((address_space(1))) uint32_t*)ga,
                (__attribute__((address_space(3))) uint32_t*)(dst + off), 16, 0, 0);
            __builtin_amdgcn_global_load_lds(
                (const __attribute__((address_space(1))) uint32_t*)gb,
                (__attribute__((address_space(3))) uint32_t*)(dst + A_ELEMS + off), 16, 0, 0);
        }
    };

    stage_bf(Sm, 0);
    int cur = 0;
    for (int t = 0; t < NT_BF; ++t) {
        __builtin_amdgcn_s_barrier();
        if (t + 1 < NT_BF) {
            stage_bf(Sm + (cur ^ 1) * TILE_U16, t + 1);
            asm volatile("s_waitcnt vmcnt(8)" ::: "memory");
        } else {
            asm volatile("s_waitcnt vmcnt(0)" ::: "memory");
        }
        __builtin_amdgcn_s_barrier();

        const u16* As_ = Sm + cur * TILE_U16;
        const u16* Bs_ = As_ + A_ELEMS;
        s16x8 af[4][2], bf[2][4];
        #pragma unroll
        for (int kk = 0; kk < 2; ++kk) {
            const int kc = (kk * 32 + kgrp) ^ sK;
            #pragma unroll
            for (int m = 0; m < 4; ++m)
                af[m][kk] = *reinterpret_cast<const s16x8*>(&As_[(wr + m * 16 + rA) * BK + kc]);
            #pragma unroll
            for (int n = 0; n < 4; ++n)
                bf[kk][n] = *reinterpret_cast<const s16x8*>(&Bs_[(wc + n * 16 + rA) * BK + kc]);
        }
        __builtin_amdgcn_s_setprio(1);
        #pragma unroll
        for (int kk = 0; kk < 2; ++kk)
            #pragma unroll
            for (int m = 0; m < 4; ++m)
                #pragma unroll
                for (int n = 0; n < 4; ++n)
                    acc[m][n] = __builtin_amdgcn_mfma_f32_16x16x32_bf16(
                        af[m][kk], bf[kk][n], acc[m][n], 0, 0, 0);
        __builtin_amdgcn_s_setprio(0);
        cur ^= 1;
    }

    // ---------------- loop B: i8 spline section (32 tiles, BK=128) -------------
    u8* SmB = reinterpret_cast<u8*>(Sm);
    auto stage_i8 = [&](u8* dst, int kt) {
        #pragma unroll
        for (int c = 0; c < 4; ++c) {
            int off = tid * 16 + c * 4096;
            int row = off >> 7, col = off & 127;
            const u8* ga = Asp_g + (size_t)(bm0 + row) * KS + kt * BKI + col;
            const u8* gb = (const u8*)Ws + (size_t)(bn0 + row) * KS + kt * BKI + col;
            __builtin_amdgcn_global_load_lds(
                (const __attribute__((address_space(1))) uint32_t*)ga,
                (__attribute__((address_space(3))) uint32_t*)(dst + off), 16, 0, 0);
            __builtin_amdgcn_global_load_lds(
                (const __attribute__((address_space(1))) uint32_t*)gb,
                (__attribute__((address_space(3))) uint32_t*)(dst + A_I8 + off), 16, 0, 0);
        }
    };

    stage_i8(SmB, 0);                   // writes buf0 region; bf16 loop done with it
    cur = 0;
    for (int t = 0; t < NT_I8; ++t) {
        __builtin_amdgcn_s_barrier();
        if (t + 1 < NT_I8) {
            stage_i8(SmB + (cur ^ 1) * TILE_I8, t + 1);
            asm volatile("s_waitcnt vmcnt(8)" ::: "memory");
        } else {
            asm volatile("s_waitcnt vmcnt(0)" ::: "memory");
        }
        __builtin_amdgcn_s_barrier();

        const u8* Aa = SmB + cur * TILE_I8;
        const u8* Bb = Aa + A_I8;
        i32x4 af[4][2], bfr[2][4];
        #pragma unroll
        for (int kk = 0; kk < 2; ++kk) {
            #pragma unroll
            for (int m = 0; m < 4; ++m) {
                const int row = wr + m * 16 + rA;
                const int col = (kk * 64 + kg8) ^ ((row & 7) << 4);
                af[m][kk] = *reinterpret_cast<const i32x4*>(&Aa[row * BKI + col]);
            }
            #pragma unroll
            for (int n = 0; n < 4; ++n) {
                const int row = wc + n * 16 + rA;
                const int col = (kk * 64 + kg8) ^ ((row & 7) << 4);
                bfr[kk][n] = *reinterpret_cast<const i32x4*>(&Bb[row * BKI + col]);
            }
        }
        __builtin_amdgcn_s_setprio(1);
        #pragma unroll
        for (int kk = 0; kk < 2; ++kk)
            #pragma unroll
            for (int m = 0; m < 4; ++m)
                #pragma unroll
                for (int n = 0; n < 4; ++n)
                    acci[m][n] = __builtin_amdgcn_mfma_i32_16x16x64_i8(
                        af[m][kk], bfr[kk][n], acci[m][n], 0, 0, 0);
        __builtin_amdgcn_s_setprio(0);
        cur ^= 1;
    }

    // epilogue: C/D layout col = lane&15, row = (lane>>4)*4 + reg
    const int rq = lane >> 4;
    const int cn = lane & 15;
    #pragma unroll
    for (int n = 0; n < 4; ++n) {
        const int col = bn0 + wc + n * 16 + cn;
        const float es = EpiS[col];
        #pragma unroll
        for (int m = 0; m < 4; ++m) {
            const int row0 = bm0 + wr + m * 16 + rq * 4;
            float* cp = C + (size_t)row0 * OUT_F + col;
            cp[0 * OUT_F] = acc[m][n][0] + (float)acci[m][n][0] * es;
            cp[1 * OUT_F] = acc[m][n][1] + (float)acci[m][n][1] * es;
            cp[2 * OUT_F] = acc[m][n][2] + (float)acci[m][n][2] * es;
            cp[3 * OUT_F] = acc[m][n][3] + (float)acci[m][n][3] * es;
        }
    }
}

extern "C" void kernel_launch(void* const* d_in, const int* in_sizes, int n_in,
                              void* d_out, int out_size, void* d_ws, size_t ws_size,
                              hipStream_t stream) {
    const float* x  = (const float*)d_in[0];
    const float* bw = (const float*)d_in[1];
    const float* sw = (const float*)d_in[2];
    const float* sc = (const float*)d_in[3];
    // d_in[4] (grid) unused: uniform knots by construction

    char* p = (char*)d_ws;
    u16*   Wb    = (u16*)p;                       p += (size_t)OUT_F * IN_F * 2;   // 0.5 MB
    char*  Ws    = p;                             p += (size_t)OUT_F * KS;         // 2 MB
    float* EpiS  = (float*)p;                     p += OUT_F * 4;
    u16*   Act_s = (u16*)p;                       p += (size_t)BATCH * IN_F * 2;   // 16.8 MB
    u8*    Act_sp= (u8*)p;                                                          // 67 MB

    prep_wb_kernel<<<(OUT_F * IN_F) / 256, 256, 0, stream>>>(bw, Wb);
    prep_ws_kernel<<<OUT_F, 256, 0, stream>>>(sw, sc, Ws, EpiS);
    prep_x_kernel<<<(BATCH * IN_F) / 256, 256, 0, stream>>>(x, Act_s, Act_sp);
    gemm_kernel<<<(BATCH / BM) * (OUT_F / BN), 256, 0, stream>>>(
        Act_s, Wb, Act_sp, Ws, EpiS, (float*)d_out);
}